// Round 1
// baseline (443.942 us; speedup 1.0000x reference)
//
#include <hip/hip_runtime.h>
#include <hip/hip_bf16.h>

#define S_LEN 4096
#define EMB   1024
#define HEAD  128
#define NB    4

typedef short bf16x8 __attribute__((ext_vector_type(8)));
typedef float f32x4  __attribute__((ext_vector_type(4)));

static __device__ __forceinline__ short f2bf(float x){
  unsigned u = __builtin_bit_cast(unsigned, x);
  u += 0x7fffu + ((u >> 16) & 1u);
  return (short)(u >> 16);
}

static __device__ __forceinline__ f32x4 mfma16(bf16x8 a, bf16x8 b, f32x4 c){
  return __builtin_amdgcn_mfma_f32_16x16x32_bf16(a, b, c, 0, 0, 0);
}

// ---------------------------------------------------------------------------
// Kernel 0: build WT_cat[384][1024] bf16 (rows = output cols of Wq|Wk|Wv,
// transposed so MFMA B-fragments are contiguous), and bias_cat[384] f32.
// The softmax scale 1/sqrt(128) is folded into Wq and bq.
// ---------------------------------------------------------------------------
__global__ void prep_w(const float* __restrict__ Wq, const float* __restrict__ bq,
                       const float* __restrict__ Wk, const float* __restrict__ bk,
                       const float* __restrict__ Wv, const float* __restrict__ bv,
                       short* __restrict__ WT, float* __restrict__ bias){
  int idx = blockIdx.x * 256 + threadIdx.x;   // 0 .. 384*1024-1
  int nc  = idx >> 10;                        // concat output col 0..383
  int k   = idx & 1023;
  int mat = nc >> 7;
  int n   = nc & 127;
  const float* W = (mat == 0) ? Wq : (mat == 1) ? Wk : Wv;
  float s = (mat == 0) ? 0.08838834764831845f : 1.0f;  // 1/sqrt(128) folded into Q
  WT[idx] = f2bf(W[k * HEAD + n] * s);
  if (idx < 384){
    int m2 = idx >> 7, n2 = idx & 127;
    const float* bsrc = (m2 == 0) ? bq : (m2 == 1) ? bk : bv;
    float s2 = (m2 == 0) ? 0.08838834764831845f : 1.0f;
    bias[idx] = bsrc[n2] * s2;
  }
}

// ---------------------------------------------------------------------------
// Kernel 1: fused QKV projection. 64 rows/block, 4 waves x 16 rows.
// Reads x once, produces Q (pre-scaled), K, V as bf16 [B*S][128].
// ---------------------------------------------------------------------------
__global__ __launch_bounds__(256) void qkv_proj(const float* __restrict__ x,
    const short* __restrict__ WT, const float* __restrict__ bias,
    short* __restrict__ Qo, short* __restrict__ Ko, short* __restrict__ Vo){
  const int wave = threadIdx.x >> 6, lane = threadIdx.x & 63;
  const int lr = lane & 15, hg = lane >> 4;
  const int row16 = blockIdx.x * 64 + wave * 16;

  const f32x4 zero = {0.f, 0.f, 0.f, 0.f};
  f32x4 acc[24];
  #pragma unroll
  for (int f = 0; f < 24; ++f) acc[f] = zero;

  const float* xp = x + (size_t)(row16 + lr) * EMB;
  for (int k0 = 0; k0 < EMB; k0 += 32){
    const float* xk = xp + k0 + hg * 8;
    float4 a0 = *(const float4*)(xk);
    float4 a1 = *(const float4*)(xk + 4);
    bf16x8 a;
    a[0] = f2bf(a0.x); a[1] = f2bf(a0.y); a[2] = f2bf(a0.z); a[3] = f2bf(a0.w);
    a[4] = f2bf(a1.x); a[5] = f2bf(a1.y); a[6] = f2bf(a1.z); a[7] = f2bf(a1.w);
    const short* wk = WT + k0 + hg * 8 + (size_t)lr * EMB;
    #pragma unroll
    for (int f = 0; f < 24; ++f){
      bf16x8 bfr = *(const bf16x8*)(wk + (size_t)f * 16 * EMB);
      acc[f] = mfma16(a, bfr, acc[f]);
    }
  }
  #pragma unroll
  for (int f = 0; f < 24; ++f){
    int mat = f >> 3;
    int col = (f & 7) * 16 + lr;
    float bb = bias[f * 16 + lr];
    short* dst = (mat == 0) ? Qo : (mat == 1) ? Ko : Vo;
    #pragma unroll
    for (int r = 0; r < 4; ++r){
      int row = row16 + hg * 4 + r;
      dst[(size_t)row * HEAD + col] = f2bf(acc[f][r] + bb);
    }
  }
}

// ---------------------------------------------------------------------------
// Kernel 2: causal flash attention. Block = 64 Q rows (4 waves x 16), KV step 32.
// K tile LDS [32][136] (pitch 272B), V transposed LDS [128][40] (pitch 80B),
// P transpose buffer per wave [16][40]. Padded pitches avoid the 16/32-way
// bank conflicts of stride-256B rows.
// ---------------------------------------------------------------------------
#define KP 136
#define VP 40
#define PP 40

__global__ __launch_bounds__(256) void attn(const short* __restrict__ Q,
    const short* __restrict__ K, const short* __restrict__ V,
    float* __restrict__ out){
  __shared__ __align__(16) short Klds[32 * KP];
  __shared__ __align__(16) short Vt[128 * VP];
  __shared__ __align__(16) short Plds[4 * 16 * PP];

  const int b  = blockIdx.y;
  const int qb = blockIdx.x * 64;
  const int tid = threadIdx.x;
  const int wave = tid >> 6, lane = tid & 63, lr = lane & 15, hg = lane >> 4;

  const short* Qb = Q + (size_t)b * S_LEN * HEAD;
  const short* Kb = K + (size_t)b * S_LEN * HEAD;
  const short* Vb = V + (size_t)b * S_LEN * HEAD;

  // Q fragments for this wave's 16 rows (A-operand: row = lane%16, k = (lane/16)*8+e)
  const int qrowA = qb + wave * 16 + lr;
  bf16x8 qf[4];
  #pragma unroll
  for (int s = 0; s < 4; ++s)
    qf[s] = *(const bf16x8*)(Qb + (size_t)qrowA * HEAD + s * 32 + hg * 8);

  const f32x4 zero = {0.f, 0.f, 0.f, 0.f};
  f32x4 acc[8];
  #pragma unroll
  for (int f = 0; f < 8; ++f) acc[f] = zero;
  float m[4]   = {-INFINITY, -INFINITY, -INFINITY, -INFINITY};
  float den[4] = {0.f, 0.f, 0.f, 0.f};

  const int tj = tid >> 4, d8 = tid & 15;
  const int jend = qb + 64;

  for (int j0 = 0; j0 < jend; j0 += 32){
    __syncthreads();   // protect previous iteration's LDS reads
    // ---- stage K tile [32][128] and V tile transposed [128][32] ----
    #pragma unroll
    for (int h = 0; h < 2; ++h){
      int jj = tj + h * 16;
      const short* ks = Kb + (size_t)(j0 + jj) * HEAD + d8 * 8;
      *(int4*)(&Klds[jj * KP + d8 * 8]) = *(const int4*)(ks);
      int4 vv = *(const int4*)(Vb + (size_t)(j0 + jj) * HEAD + d8 * 8);
      short* vs = (short*)&vv;
      #pragma unroll
      for (int e = 0; e < 8; ++e) Vt[(d8 * 8 + e) * VP + jj] = vs[e];
    }
    __syncthreads();

    // ---- scores: two 16x16 subtiles, K-dim = 128 in 4 slices ----
    f32x4 sc[2];
    #pragma unroll
    for (int sub = 0; sub < 2; ++sub){
      sc[sub] = zero;
      #pragma unroll
      for (int sl = 0; sl < 4; ++sl){
        bf16x8 kf = *(const bf16x8*)(&Klds[(sub * 16 + lr) * KP + sl * 32 + hg * 8]);
        sc[sub] = mfma16(qf[sl], kf, sc[sub]);
      }
    }

    // ---- causal mask (D row = qb+wave*16+hg*4+r, col j = j0+sub*16+lr) ----
    const int qrow0 = qb + wave * 16 + hg * 4;
    #pragma unroll
    for (int sub = 0; sub < 2; ++sub){
      int jg = j0 + sub * 16 + lr;
      #pragma unroll
      for (int r = 0; r < 4; ++r)
        if (jg > qrow0 + r) sc[sub][r] = -INFINITY;
    }

    // ---- online softmax (row reduction across 16-lane groups) ----
    float mt[4], al[4], p0[4], p1[4], sm[4];
    #pragma unroll
    for (int r = 0; r < 4; ++r) mt[r] = fmaxf(sc[0][r], sc[1][r]);
    #pragma unroll
    for (int msk = 1; msk < 16; msk <<= 1){
      #pragma unroll
      for (int r = 0; r < 4; ++r) mt[r] = fmaxf(mt[r], __shfl_xor(mt[r], msk));
    }
    #pragma unroll
    for (int r = 0; r < 4; ++r){
      float mn = fmaxf(m[r], mt[r]);
      al[r] = __expf(m[r] - mn);
      m[r] = mn;
      p0[r] = __expf(sc[0][r] - mn);
      p1[r] = __expf(sc[1][r] - mn);
      sm[r] = p0[r] + p1[r];
    }
    #pragma unroll
    for (int msk = 1; msk < 16; msk <<= 1){
      #pragma unroll
      for (int r = 0; r < 4; ++r) sm[r] += __shfl_xor(sm[r], msk);
    }
    #pragma unroll
    for (int r = 0; r < 4; ++r) den[r] = den[r] * al[r] + sm[r];
    #pragma unroll
    for (int f = 0; f < 8; ++f){
      #pragma unroll
      for (int r = 0; r < 4; ++r) acc[f][r] *= al[r];
    }

    // ---- transpose P through LDS into A-fragment layout ----
    #pragma unroll
    for (int r = 0; r < 4; ++r){
      Plds[wave * 16 * PP + (hg * 4 + r) * PP + lr]      = f2bf(p0[r]);
      Plds[wave * 16 * PP + (hg * 4 + r) * PP + 16 + lr] = f2bf(p1[r]);
    }
    bf16x8 pf = *(const bf16x8*)(&Plds[wave * 16 * PP + lr * PP + hg * 8]);

    // ---- PV: O[16][128] += P[16][32] * V[32][128] ----
    #pragma unroll
    for (int f = 0; f < 8; ++f){
      bf16x8 vf = *(const bf16x8*)(&Vt[(f * 16 + lr) * VP + hg * 8]);
      acc[f] = mfma16(pf, vf, acc[f]);
    }
  }

  // ---- epilogue ----
  float* ob = out + (size_t)b * S_LEN * HEAD;
  #pragma unroll
  for (int f = 0; f < 8; ++f){
    int col = f * 16 + lr;
    #pragma unroll
    for (int r = 0; r < 4; ++r){
      int row = qb + wave * 16 + hg * 4 + r;
      ob[(size_t)row * HEAD + col] = acc[f][r] / den[r];
    }
  }
}

// ---------------------------------------------------------------------------
extern "C" void kernel_launch(void* const* d_in, const int* in_sizes, int n_in,
                              void* d_out, int out_size, void* d_ws, size_t ws_size,
                              hipStream_t stream){
  const float* x  = (const float*)d_in[0];
  const float* Wq = (const float*)d_in[1];
  const float* bq = (const float*)d_in[2];
  const float* Wk = (const float*)d_in[3];
  const float* bk = (const float*)d_in[4];
  const float* Wv = (const float*)d_in[5];
  const float* bv = (const float*)d_in[6];
  float* out = (float*)d_out;

  char* ws = (char*)d_ws;
  short* WT   = (short*)(ws);                      // 384*1024*2 = 768 KB
  float* bias = (float*)(ws + 786432);             // 1.5 KB
  short* Qb   = (short*)(ws + (1u << 20));         // 4 MB each
  short* Kb   = (short*)(ws + (1u << 20) + 4194304u);
  short* Vb   = (short*)(ws + (1u << 20) + 8388608u);

  prep_w<<<1536, 256, 0, stream>>>(Wq, bq, Wk, bk, Wv, bv, WT, bias);
  qkv_proj<<<256, 256, 0, stream>>>(x, WT, bias, Qb, Kb, Vb);
  attn<<<dim3(64, NB), 256, 0, stream>>>(Qb, Kb, Vb, out);
}

// Round 2
// 339.447 us; speedup vs baseline: 1.3078x; 1.3078x over previous
//
#include <hip/hip_runtime.h>
#include <hip/hip_bf16.h>
#include <math.h>

#define S_LEN 4096
#define EMB   1024
#define HEAD  128

typedef short bf16x8 __attribute__((ext_vector_type(8)));
typedef float f32x4  __attribute__((ext_vector_type(4)));

static __device__ __forceinline__ short f2bf(float x){
  unsigned u = __builtin_bit_cast(unsigned, x);
  u += 0x7fffu + ((u >> 16) & 1u);
  return (short)(u >> 16);
}

static __device__ __forceinline__ f32x4 mfma16(bf16x8 a, bf16x8 b, f32x4 c){
  return __builtin_amdgcn_mfma_f32_16x16x32_bf16(a, b, c, 0, 0, 0);
}

// ---------------------------------------------------------------------------
// Kernel 0: WT_cat[384][1024] bf16 (transposed, Q pre-scaled by 1/sqrt(128)),
// bias_cat[384] f32.
// ---------------------------------------------------------------------------
__global__ void prep_w(const float* __restrict__ Wq, const float* __restrict__ bq,
                       const float* __restrict__ Wk, const float* __restrict__ bk,
                       const float* __restrict__ Wv, const float* __restrict__ bv,
                       short* __restrict__ WT, float* __restrict__ bias){
  int idx = blockIdx.x * 256 + threadIdx.x;   // 0 .. 384*1024-1
  int nc  = idx >> 10;
  int k   = idx & 1023;
  int mat = nc >> 7;
  int n   = nc & 127;
  const float* W = (mat == 0) ? Wq : (mat == 1) ? Wk : Wv;
  float s = (mat == 0) ? 0.08838834764831845f : 1.0f;
  WT[idx] = f2bf(W[k * HEAD + n] * s);
  if (idx < 384){
    int m2 = idx >> 7, n2 = idx & 127;
    const float* bsrc = (m2 == 0) ? bq : (m2 == 1) ? bk : bv;
    float s2 = (m2 == 0) ? 0.08838834764831845f : 1.0f;
    bias[idx] = bsrc[n2] * s2;
  }
}

// ---------------------------------------------------------------------------
// Kernel 1: fused QKV projection. 8 waves/block (4 row-groups x 2 col-groups),
// 64 rows/block. Q,K written row-major bf16 [B*S][128]; V written TRANSPOSED
// as VT [B][128][4096] bf16 so attention's PV B-fragments are contiguous.
// ---------------------------------------------------------------------------
__global__ __launch_bounds__(512) void qkv_proj(const float* __restrict__ x,
    const short* __restrict__ WT, const float* __restrict__ bias,
    short* __restrict__ Qo, short* __restrict__ Ko, short* __restrict__ VTo){
  const int wave = threadIdx.x >> 6, lane = threadIdx.x & 63;
  const int lr = lane & 15, hg = lane >> 4;
  const int row16 = blockIdx.x * 64 + (wave >> 1) * 16;
  const int fbase = (wave & 1) * 12;

  const f32x4 zero = {0.f, 0.f, 0.f, 0.f};
  f32x4 acc[12];
  #pragma unroll
  for (int f = 0; f < 12; ++f) acc[f] = zero;

  const float* xp = x + (size_t)(row16 + lr) * EMB;
  for (int k0 = 0; k0 < EMB; k0 += 32){
    const float* xk = xp + k0 + hg * 8;
    float4 a0 = *(const float4*)(xk);
    float4 a1 = *(const float4*)(xk + 4);
    bf16x8 a;
    a[0] = f2bf(a0.x); a[1] = f2bf(a0.y); a[2] = f2bf(a0.z); a[3] = f2bf(a0.w);
    a[4] = f2bf(a1.x); a[5] = f2bf(a1.y); a[6] = f2bf(a1.z); a[7] = f2bf(a1.w);
    const short* wk = WT + k0 + hg * 8 + (size_t)(fbase * 16 + lr) * EMB;
    #pragma unroll
    for (int fi = 0; fi < 12; ++fi){
      bf16x8 bfr = *(const bf16x8*)(wk + (size_t)fi * 16 * EMB);
      acc[fi] = mfma16(a, bfr, acc[fi]);
    }
  }
  #pragma unroll
  for (int fi = 0; fi < 12; ++fi){
    int f = fbase + fi;
    int mat = f >> 3;
    int col = (f & 7) * 16 + lr;
    float bb = bias[f * 16 + lr];
    if (mat < 2){
      short* dst = (mat == 0) ? Qo : Ko;
      #pragma unroll
      for (int r = 0; r < 4; ++r){
        int row = row16 + hg * 4 + r;
        dst[(size_t)row * HEAD + col] = f2bf(acc[fi][r] + bb);
      }
    } else {
      #pragma unroll
      for (int r = 0; r < 4; ++r){
        int row = row16 + hg * 4 + r;
        int b = row >> 12, s = row & 4095;
        VTo[((size_t)(b * HEAD + col)) * S_LEN + s] = f2bf(acc[fi][r] + bb);
      }
    }
  }
}

// ---------------------------------------------------------------------------
// Kernel 2: split-KV causal flash partials. Work item = 1 WAVE = 16 Q rows x
// <=1024 KV. Per batch: tile t (t=0..255) has ceil((t+1)/64) chunks -> 640
// items/batch, 2560 waves total (balanced, ~2.5 waves/SIMD). No block-level
// sync; K read direct from global (L2-resident), V via pre-transposed VT.
// Only LDS: per-wave padded P-transpose buffer (pitch 68 shorts).
// ---------------------------------------------------------------------------
#define PP 68

__global__ __launch_bounds__(256) void attn_partial(const short* __restrict__ Q,
    const short* __restrict__ K, const short* __restrict__ VT,
    float* __restrict__ Opart, float* __restrict__ ML){
  __shared__ __align__(16) short Plds[4][16 * PP];

  const int wave = threadIdx.x >> 6, lane = threadIdx.x & 63;
  const int lr = lane & 15, hg = lane >> 4;
  const int wid = blockIdx.x * 4 + wave;   // 0..639 per batch
  const int b   = blockIdx.y;

  int t, c;
  if (wid < 64)      { t = wid;                 c = 0; }
  else if (wid < 192){ int r = wid - 64;  t = 64  + (r >> 1); c = r & 1; }
  else if (wid < 384){ int r = wid - 192; int q3 = r / 3; t = 128 + q3; c = r - q3 * 3; }
  else               { int r = wid - 384; t = 192 + (r >> 2); c = r & 3; }

  const int qr0  = t * 16;
  const int kvlo = c << 10;
  const int kvhi = min(kvlo + 1024, qr0 + 16);

  const short* Qb = Q  + ((size_t)b * S_LEN + qr0) * HEAD;
  const short* Kb = K  + (size_t)b * S_LEN * HEAD;
  const short* Vb = VT + (size_t)b * HEAD * S_LEN;

  bf16x8 qf[4];
  #pragma unroll
  for (int sl = 0; sl < 4; ++sl)
    qf[sl] = *(const bf16x8*)(Qb + (size_t)lr * HEAD + sl * 32 + hg * 8);

  const f32x4 zero = {0.f, 0.f, 0.f, 0.f};
  f32x4 acc[8];
  #pragma unroll
  for (int f = 0; f < 8; ++f) acc[f] = zero;
  float m[4]   = {-INFINITY, -INFINITY, -INFINITY, -INFINITY};
  float den[4] = {0.f, 0.f, 0.f, 0.f};

  short* Pw = &Plds[wave][0];
  const int qrow0 = qr0 + hg * 4;

  for (int j0 = kvlo; j0 < kvhi; j0 += 64){
    // ---- scores: 4 kv-subtiles x 4 d-slices, K direct from global (L2) ----
    f32x4 sc[4];
    #pragma unroll
    for (int sub = 0; sub < 4; ++sub){
      sc[sub] = zero;
      #pragma unroll
      for (int sl = 0; sl < 4; ++sl){
        bf16x8 kf = *(const bf16x8*)(Kb + (size_t)(j0 + sub * 16 + lr) * HEAD + sl * 32 + hg * 8);
        sc[sub] = mfma16(qf[sl], kf, sc[sub]);
      }
    }

    // ---- causal mask ----
    #pragma unroll
    for (int sub = 0; sub < 4; ++sub){
      int jg = j0 + sub * 16 + lr;
      #pragma unroll
      for (int r = 0; r < 4; ++r)
        if (jg > qrow0 + r) sc[sub][r] = -INFINITY;
    }

    // ---- online softmax (16-lane-group reduce) ----
    float mt[4];
    #pragma unroll
    for (int r = 0; r < 4; ++r)
      mt[r] = fmaxf(fmaxf(sc[0][r], sc[1][r]), fmaxf(sc[2][r], sc[3][r]));
    #pragma unroll
    for (int msk = 1; msk < 16; msk <<= 1){
      #pragma unroll
      for (int r = 0; r < 4; ++r) mt[r] = fmaxf(mt[r], __shfl_xor(mt[r], msk));
    }
    float al[4], sm[4], p[4][4];
    #pragma unroll
    for (int r = 0; r < 4; ++r){
      float mn = fmaxf(m[r], mt[r]);
      al[r] = __expf(m[r] - mn);
      m[r] = mn;
      #pragma unroll
      for (int sub = 0; sub < 4; ++sub) p[sub][r] = __expf(sc[sub][r] - mn);
      sm[r] = (p[0][r] + p[1][r]) + (p[2][r] + p[3][r]);
    }
    #pragma unroll
    for (int msk = 1; msk < 16; msk <<= 1){
      #pragma unroll
      for (int r = 0; r < 4; ++r) sm[r] += __shfl_xor(sm[r], msk);
    }
    #pragma unroll
    for (int r = 0; r < 4; ++r) den[r] = den[r] * al[r] + sm[r];
    #pragma unroll
    for (int f = 0; f < 8; ++f){
      #pragma unroll
      for (int r = 0; r < 4; ++r) acc[f][r] *= al[r];
    }

    // ---- transpose P through per-wave LDS (no barrier needed) ----
    #pragma unroll
    for (int sub = 0; sub < 4; ++sub){
      #pragma unroll
      for (int r = 0; r < 4; ++r)
        Pw[(hg * 4 + r) * PP + sub * 16 + lr] = f2bf(p[sub][r]);
    }
    bf16x8 pf0 = *(const bf16x8*)(&Pw[lr * PP + hg * 8]);
    bf16x8 pf1 = *(const bf16x8*)(&Pw[lr * PP + 32 + hg * 8]);

    // ---- PV: O[16][128] += P[16][64] * V[64][128], V^T fragments contiguous ----
    #pragma unroll
    for (int f = 0; f < 8; ++f){
      bf16x8 vf0 = *(const bf16x8*)(Vb + (size_t)(f * 16 + lr) * S_LEN + j0 + hg * 8);
      acc[f] = mfma16(pf0, vf0, acc[f]);
      bf16x8 vf1 = *(const bf16x8*)(Vb + (size_t)(f * 16 + lr) * S_LEN + j0 + 32 + hg * 8);
      acc[f] = mfma16(pf1, vf1, acc[f]);
    }
  }

  // ---- write partial (unnormalized O, m, l) ----
  const int pidx = b * 640 + wid;
  float* Op = Opart + (size_t)pidx * 2048;
  #pragma unroll
  for (int f = 0; f < 8; ++f){
    #pragma unroll
    for (int r = 0; r < 4; ++r)
      Op[(hg * 4 + r) * 128 + f * 16 + lr] = acc[f][r];
  }
  if (lr == 0){
    #pragma unroll
    for (int r = 0; r < 4; ++r){
      ML[pidx * 32 + hg * 4 + r]      = m[r];
      ML[pidx * 32 + 16 + hg * 4 + r] = den[r];
    }
  }
}

// ---------------------------------------------------------------------------
// Kernel 3: combine partials. Block = one 16-row tile; thread = (row, 8 cols).
// ---------------------------------------------------------------------------
__global__ __launch_bounds__(256) void combine(const float* __restrict__ Opart,
    const float* __restrict__ ML, float* __restrict__ out){
  const int t = blockIdx.x, b = blockIdx.y;
  const int row = threadIdx.x >> 4, cb = threadIdx.x & 15;
  const int kmax = (t >> 6) + 1;
  int base;
  if (t < 64)       base = t;
  else if (t < 128) base = 64  + (t - 64) * 2;
  else if (t < 192) base = 192 + (t - 128) * 3;
  else              base = 384 + (t - 192) * 4;
  base += b * 640;

  float M = -INFINITY;
  for (int cc = 0; cc < kmax; ++cc)
    M = fmaxf(M, ML[(base + cc) * 32 + row]);

  float L = 0.f;
  float o[8];
  #pragma unroll
  for (int e = 0; e < 8; ++e) o[e] = 0.f;

  for (int cc = 0; cc < kmax; ++cc){
    float mc = ML[(base + cc) * 32 + row];
    float lc = ML[(base + cc) * 32 + 16 + row];
    float scl = __expf(mc - M);
    L += lc * scl;
    const float* op = Opart + (size_t)(base + cc) * 2048 + row * 128 + cb * 8;
    float4 v0 = *(const float4*)(op);
    float4 v1 = *(const float4*)(op + 4);
    o[0] += scl * v0.x; o[1] += scl * v0.y; o[2] += scl * v0.z; o[3] += scl * v0.w;
    o[4] += scl * v1.x; o[5] += scl * v1.y; o[6] += scl * v1.z; o[7] += scl * v1.w;
  }
  float inv = 1.f / L;
  float* dst = out + ((size_t)b * S_LEN + t * 16 + row) * HEAD + cb * 8;
  float4 w0 = { o[0] * inv, o[1] * inv, o[2] * inv, o[3] * inv };
  float4 w1 = { o[4] * inv, o[5] * inv, o[6] * inv, o[7] * inv };
  *(float4*)(dst)     = w0;
  *(float4*)(dst + 4) = w1;
}

// ---------------------------------------------------------------------------
extern "C" void kernel_launch(void* const* d_in, const int* in_sizes, int n_in,
                              void* d_out, int out_size, void* d_ws, size_t ws_size,
                              hipStream_t stream){
  const float* x  = (const float*)d_in[0];
  const float* Wq = (const float*)d_in[1];
  const float* bq = (const float*)d_in[2];
  const float* Wk = (const float*)d_in[3];
  const float* bk = (const float*)d_in[4];
  const float* Wv = (const float*)d_in[5];
  const float* bv = (const float*)d_in[6];
  float* out = (float*)d_out;

  char* ws = (char*)d_ws;
  short* WT    = (short*)(ws);                         // 768 KB
  float* bias  = (float*)(ws + 786432);                // 1.5 KB
  short* Qb    = (short*)(ws + (1u << 20));            // 4 MB
  short* Kb    = (short*)(ws + (1u << 20) + 4194304u); // 4 MB
  short* VTb   = (short*)(ws + (1u << 20) + 8388608u); // 4 MB
  float* Opart = (float*)(ws + 13631488u);             // 2560*2048*4 = 20 MB
  float* ML    = (float*)(ws + 13631488u + 20971520u); // 320 KB

  prep_w<<<1536, 256, 0, stream>>>(Wq, bq, Wk, bk, Wv, bv, WT, bias);
  qkv_proj<<<256, 512, 0, stream>>>(x, WT, bias, Qb, Kb, VTb);
  attn_partial<<<dim3(160, 4), 256, 0, stream>>>(Qb, Kb, VTb, Opart, ML);
  combine<<<dim3(256, 4), 256, 0, stream>>>(Opart, ML, out);
}

// Round 4
// 149.289 us; speedup vs baseline: 2.9737x; 2.2738x over previous
//
#include <hip/hip_runtime.h>
#include <hip/hip_bf16.h>
#include <math.h>

#define S_LEN 4096
#define EMB   1024
#define HEAD  128

typedef short bf16x8 __attribute__((ext_vector_type(8)));
typedef float f32x4  __attribute__((ext_vector_type(4)));

static __device__ __forceinline__ short f2bf(float x){
  unsigned u = __builtin_bit_cast(unsigned, x);
  u += 0x7fffu + ((u >> 16) & 1u);
  return (short)(u >> 16);
}
static __device__ __forceinline__ f32x4 mfma16(bf16x8 a, bf16x8 b, f32x4 c){
  return __builtin_amdgcn_mfma_f32_16x16x32_bf16(a, b, c, 0, 0, 0);
}
static __device__ __forceinline__ void gload16(const void* g, void* l){
  __builtin_amdgcn_global_load_lds((const __attribute__((address_space(1))) unsigned*)g,
                                   (__attribute__((address_space(3))) unsigned*)l, 16, 0, 0);
}

// ---------------------------------------------------------------------------
// Kernel 0: WT_cat[384][1024] bf16 (transposed, Q pre-scaled by 1/sqrt(128)),
// bias_cat[384] f32.
// ---------------------------------------------------------------------------
__global__ void prep_w(const float* __restrict__ Wq, const float* __restrict__ bq,
                       const float* __restrict__ Wk, const float* __restrict__ bk,
                       const float* __restrict__ Wv, const float* __restrict__ bv,
                       short* __restrict__ WT, float* __restrict__ bias){
  int idx = blockIdx.x * 256 + threadIdx.x;
  int nc  = idx >> 10;
  int k   = idx & 1023;
  int mat = nc >> 7;
  int n   = nc & 127;
  const float* W = (mat == 0) ? Wq : (mat == 1) ? Wk : Wv;
  float s = (mat == 0) ? 0.08838834764831845f : 1.0f;
  WT[idx] = f2bf(W[k * HEAD + n] * s);
  if (idx < 384){
    int m2 = idx >> 7, n2 = idx & 127;
    const float* bsrc = (m2 == 0) ? bq : (m2 == 1) ? bk : bv;
    float s2 = (m2 == 0) ? 0.08838834764831845f : 1.0f;
    bias[idx] = bsrc[n2] * s2;
  }
}

// ---------------------------------------------------------------------------
// Kernel 1: fused QKV projection, double-buffered LDS staging.
// Block = 512 thr (8 waves = 4 rowgroups x 2 colgroups), 64 x-rows.
// WT chunk [384][64k] staged fragment-ordered (48KB); x chunk [64][64k] f32
// row-major + XOR-swizzled reads (16KB). V epilogue -> padded LDS bounce ->
// coalesced transposed VT [B][128][4096] stores.
// ---------------------------------------------------------------------------
__global__ __launch_bounds__(512) void qkv_proj(const float* __restrict__ x,
    const short* __restrict__ WT, const float* __restrict__ bias,
    short* __restrict__ Qo, short* __restrict__ Ko, short* __restrict__ VTo){
  __shared__ __align__(16) short Wl[2][24576];   // 48KB each
  __shared__ __align__(16) float Xl[2][4096];    // 16KB each
  __shared__ __align__(16) short Vb[128 * 72];   // 18KB bounce

  const int tid = threadIdx.x;
  const int wave = tid >> 6, lane = tid & 63, lr = lane & 15, hg = lane >> 4;
  const int rg = wave >> 1, cg = wave & 1, fbase = cg * 12;
  const int row0 = blockIdx.x * 64;

  const f32x4 zero = {0.f, 0.f, 0.f, 0.f};
  f32x4 acc[12];
  #pragma unroll
  for (int f = 0; f < 12; ++f) acc[f] = zero;

#define QKV_STAGE(buf, k0)                                                         \
  {                                                                                \
    _Pragma("unroll")                                                              \
    for (int s = 0; s < 6; ++s){                                                   \
      int slot = s * 8 + wave;                                                     \
      int ff = slot >> 1, ks = slot & 1;                                           \
      gload16(WT + (size_t)(ff * 16 + lr) * 1024 + (k0) + ks * 32 + hg * 8,        \
              &Wl[buf][slot * 512]);                                               \
    }                                                                              \
    _Pragma("unroll")                                                              \
    for (int q = 0; q < 2; ++q){                                                   \
      int rr = (wave * 2 + q) * 4 + hg;                                            \
      int cs = lr ^ (rr & 15);                                                     \
      gload16(x + (size_t)(row0 + rr) * 1024 + (k0) + cs * 4,                      \
              &Xl[buf][(wave * 2 + q) * 256]);                                     \
    }                                                                              \
  }

  QKV_STAGE(0, 0)
  asm volatile("s_waitcnt vmcnt(0)" ::: "memory");
  __syncthreads();

  int cur = 0;
  const int xr = rg * 16 + lr;
  for (int t = 0; t < 16; ++t){
    if (t < 15) QKV_STAGE(cur ^ 1, (t + 1) * 64)
    bf16x8 a[2];
    #pragma unroll
    for (int ks = 0; ks < 2; ++ks){
      int s0 = ks * 8 + hg * 2;
      f32x4 xa = *(const f32x4*)&Xl[cur][xr * 64 + ((s0 ^ lr) << 2)];
      f32x4 xb = *(const f32x4*)&Xl[cur][xr * 64 + (((s0 + 1) ^ lr) << 2)];
      a[ks][0] = f2bf(xa[0]); a[ks][1] = f2bf(xa[1]);
      a[ks][2] = f2bf(xa[2]); a[ks][3] = f2bf(xa[3]);
      a[ks][4] = f2bf(xb[0]); a[ks][5] = f2bf(xb[1]);
      a[ks][6] = f2bf(xb[2]); a[ks][7] = f2bf(xb[3]);
    }
    #pragma unroll
    for (int fi = 0; fi < 12; ++fi){
      #pragma unroll
      for (int ks = 0; ks < 2; ++ks){
        bf16x8 bfr = *(const bf16x8*)&Wl[cur][((fbase + fi) * 2 + ks) * 512 + lane * 8];
        acc[fi] = mfma16(a[ks], bfr, acc[fi]);
      }
    }
    asm volatile("s_waitcnt vmcnt(0)" ::: "memory");
    __syncthreads();
    cur ^= 1;
  }

  // epilogue: Q/K row-major stores; V through LDS bounce -> transposed VT
  #pragma unroll
  for (int fi = 0; fi < 12; ++fi){
    int f = fbase + fi;
    float bb = bias[f * 16 + lr];
    if (f < 16){
      short* dst = (f < 8) ? Qo : Ko;
      int col = (f & 7) * 16 + lr;
      #pragma unroll
      for (int r = 0; r < 4; ++r)
        dst[(size_t)(row0 + rg * 16 + hg * 4 + r) * HEAD + col] = f2bf(acc[fi][r] + bb);
    } else {
      int vcol = (f - 16) * 16 + lr;
      #pragma unroll
      for (int r = 0; r < 4; ++r)
        Vb[vcol * 72 + rg * 16 + hg * 4 + r] = f2bf(acc[fi][r] + bb);
    }
  }
  __syncthreads();
  {
    int vcol = tid >> 2, sq = tid & 3;
    bf16x8 v0 = *(const bf16x8*)&Vb[vcol * 72 + sq * 16];
    bf16x8 v1 = *(const bf16x8*)&Vb[vcol * 72 + sq * 16 + 8];
    int bb2 = row0 >> 12, ss = row0 & 4095;
    short* d = VTo + ((size_t)(bb2 * HEAD + vcol)) * S_LEN + ss + sq * 16;
    *(bf16x8*)d = v0;
    *(bf16x8*)(d + 8) = v1;
  }
}

// ---------------------------------------------------------------------------
// Kernel 2: split-KV causal flash, LDS-staged. Block = 64 Q rows (4 waves),
// one KV chunk (<=1024), step 64. K and V^T tiles staged fragment-ordered
// via global_load_lds (16 slots x 1KB each), double-buffered: ds_read_b128
// is linear (zero conflicts). Heavy-first block mapping for tail balance.
// ---------------------------------------------------------------------------
#define PP 68

__global__ __launch_bounds__(256) void attn(const short* __restrict__ Q,
    const short* __restrict__ K, const short* __restrict__ VT,
    float* __restrict__ Opart, float* __restrict__ ML){
  __shared__ __align__(16) short Kl[2][8192];
  __shared__ __align__(16) short Vl[2][8192];
  __shared__ __align__(16) short Pl[4][16 * PP];

  const int tid = threadIdx.x;
  const int wave = tid >> 6, lane = tid & 63, lr = lane & 15, hg = lane >> 4;
  const int b = blockIdx.y;
  const int i = blockIdx.x;

  // heavy-first map i -> (t, c): full-16-step blocks first
  int t, c;
  if      (i < 49)  { t = 15 + i;       c = 0; }
  else if (i < 82)  { t = 31 + (i - 49); c = 1; }
  else if (i < 99)  { t = 47 + (i - 82); c = 2; }
  else if (i < 100) { t = 63;            c = 3; }
  else if (i < 115) { t = i - 100;       c = 0; }
  else if (i < 130) { t = 16 + (i - 115); c = 1; }
  else if (i < 145) { t = 32 + (i - 130); c = 2; }
  else              { t = 48 + (i - 145); c = 3; }

  const int qt0  = t * 64;
  const int kvlo = c * 1024;
  const int kvhi = min(kvlo + 1024, qt0 + 64);
  const int nstep = (kvhi - kvlo) >> 6;

  const short* Qg = Q  + ((size_t)b * S_LEN + qt0 + wave * 16) * HEAD;
  const short* Kg = K  + (size_t)b * S_LEN * HEAD;
  const short* Vg = VT + (size_t)b * HEAD * S_LEN;

  bf16x8 qf[4];
  #pragma unroll
  for (int sl = 0; sl < 4; ++sl)
    qf[sl] = *(const bf16x8*)(Qg + (size_t)lr * HEAD + sl * 32 + hg * 8);

#define ATTN_STAGE(buf, j0)                                                        \
  {                                                                                \
    _Pragma("unroll")                                                              \
    for (int s = 0; s < 4; ++s){                                                   \
      int slot = wave * 4 + s;                                                     \
      gload16(Kg + (size_t)((j0) + (slot >> 2) * 16 + lr) * HEAD + (slot & 3) * 32 + hg * 8, \
              &Kl[buf][slot * 512]);                                               \
    }                                                                              \
    _Pragma("unroll")                                                              \
    for (int s = 0; s < 4; ++s){                                                   \
      int slot = wave * 4 + s;                                                     \
      gload16(Vg + (size_t)((slot >> 1) * 16 + lr) * S_LEN + (j0) + (slot & 1) * 32 + hg * 8, \
              &Vl[buf][slot * 512]);                                               \
    }                                                                              \
  }

  ATTN_STAGE(0, kvlo)
  asm volatile("s_waitcnt vmcnt(0)" ::: "memory");
  __syncthreads();

  const f32x4 zero = {0.f, 0.f, 0.f, 0.f};
  f32x4 acc[8];
  #pragma unroll
  for (int f = 0; f < 8; ++f) acc[f] = zero;
  float m[4]   = {-INFINITY, -INFINITY, -INFINITY, -INFINITY};
  float den[4] = {0.f, 0.f, 0.f, 0.f};

  short* Pw = &Pl[wave][0];
  const int qrow0 = qt0 + wave * 16 + hg * 4;

  int cur = 0;
  for (int st = 0; st < nstep; ++st){
    const int j0 = kvlo + st * 64;
    if (st + 1 < nstep) ATTN_STAGE(cur ^ 1, j0 + 64)

    // ---- QK^T: 4 kv-subtiles x 4 d-slices, linear ds_read_b128 ----
    f32x4 sc[4];
    #pragma unroll
    for (int sub = 0; sub < 4; ++sub){
      sc[sub] = zero;
      #pragma unroll
      for (int sl = 0; sl < 4; ++sl){
        bf16x8 kf = *(const bf16x8*)&Kl[cur][(sub * 4 + sl) * 512 + lane * 8];
        sc[sub] = mfma16(qf[sl], kf, sc[sub]);
      }
    }

    // ---- causal mask (only the diagonal step) ----
    if (j0 == qt0){
      #pragma unroll
      for (int sub = 0; sub < 4; ++sub){
        int jg = j0 + sub * 16 + lr;
        #pragma unroll
        for (int r = 0; r < 4; ++r)
          if (jg > qrow0 + r) sc[sub][r] = -INFINITY;
      }
    }

    // ---- online softmax (16-lane-group reduce) ----
    float mt[4];
    #pragma unroll
    for (int r = 0; r < 4; ++r)
      mt[r] = fmaxf(fmaxf(sc[0][r], sc[1][r]), fmaxf(sc[2][r], sc[3][r]));
    #pragma unroll
    for (int msk = 1; msk < 16; msk <<= 1){
      #pragma unroll
      for (int r = 0; r < 4; ++r) mt[r] = fmaxf(mt[r], __shfl_xor(mt[r], msk));
    }
    float al[4], sm[4], p[4][4];
    #pragma unroll
    for (int r = 0; r < 4; ++r){
      float mn = fmaxf(m[r], mt[r]);
      al[r] = __expf(m[r] - mn);
      m[r] = mn;
      #pragma unroll
      for (int sub = 0; sub < 4; ++sub) p[sub][r] = __expf(sc[sub][r] - mn);
      sm[r] = (p[0][r] + p[1][r]) + (p[2][r] + p[3][r]);
    }
    #pragma unroll
    for (int msk = 1; msk < 16; msk <<= 1){
      #pragma unroll
      for (int r = 0; r < 4; ++r) sm[r] += __shfl_xor(sm[r], msk);
    }
    #pragma unroll
    for (int r = 0; r < 4; ++r) den[r] = den[r] * al[r] + sm[r];
    #pragma unroll
    for (int f = 0; f < 8; ++f){
      #pragma unroll
      for (int r = 0; r < 4; ++r) acc[f][r] *= al[r];
    }

    // ---- transpose P through per-wave LDS ----
    #pragma unroll
    for (int sub = 0; sub < 4; ++sub){
      #pragma unroll
      for (int r = 0; r < 4; ++r)
        Pw[(hg * 4 + r) * PP + sub * 16 + lr] = f2bf(p[sub][r]);
    }
    bf16x8 pf0 = *(const bf16x8*)&Pw[lr * PP + hg * 8];
    bf16x8 pf1 = *(const bf16x8*)&Pw[lr * PP + 32 + hg * 8];

    // ---- PV from fragment-ordered V slots ----
    #pragma unroll
    for (int f = 0; f < 8; ++f){
      bf16x8 vf0 = *(const bf16x8*)&Vl[cur][(f * 2) * 512 + lane * 8];
      acc[f] = mfma16(pf0, vf0, acc[f]);
      bf16x8 vf1 = *(const bf16x8*)&Vl[cur][(f * 2 + 1) * 512 + lane * 8];
      acc[f] = mfma16(pf1, vf1, acc[f]);
    }

    asm volatile("s_waitcnt vmcnt(0)" ::: "memory");
    __syncthreads();
    cur ^= 1;
  }

  // ---- write partial (unnormalized O, m, l) ----
  const int pidx = b * 160 + i;
  float* Op = Opart + (size_t)pidx * 8192;
  #pragma unroll
  for (int f = 0; f < 8; ++f){
    #pragma unroll
    for (int r = 0; r < 4; ++r)
      Op[(wave * 16 + hg * 4 + r) * 128 + f * 16 + lr] = acc[f][r];
  }
  if (lr == 0){
    #pragma unroll
    for (int r = 0; r < 4; ++r){
      ML[pidx * 128 + wave * 16 + hg * 4 + r]      = m[r];
      ML[pidx * 128 + 64 + wave * 16 + hg * 4 + r] = den[r];
    }
  }
}

// ---------------------------------------------------------------------------
// Kernel 3: combine partials. Block = one 64-row tile, 512 threads.
// ---------------------------------------------------------------------------
__global__ __launch_bounds__(512) void combine(const float* __restrict__ Opart,
    const float* __restrict__ ML, float* __restrict__ out){
  const int t = blockIdx.x, b = blockIdx.y;
  const int row = threadIdx.x >> 3;
  const int cgp = threadIdx.x & 7;
  const int nc = (t >> 4) + 1;
  const int fb0 = 0, fb1 = 49, fb2 = 82, fb3 = 99;

  float M = -INFINITY;
  for (int cc = 0; cc < nc; ++cc){
    int fbv = (cc == 0) ? fb0 : (cc == 1) ? fb1 : (cc == 2) ? fb2 : fb3;
    int ii = (t >= 16 * cc + 15) ? (fbv + t - (16 * cc + 15)) : (100 + t - cc);
    M = fmaxf(M, ML[(b * 160 + ii) * 128 + row]);
  }
  float L = 0.f;
  float o[16];
  #pragma unroll
  for (int e = 0; e < 16; ++e) o[e] = 0.f;
  for (int cc = 0; cc < nc; ++cc){
    int fbv = (cc == 0) ? fb0 : (cc == 1) ? fb1 : (cc == 2) ? fb2 : fb3;
    int ii = (t >= 16 * cc + 15) ? (fbv + t - (16 * cc + 15)) : (100 + t - cc);
    int id = b * 160 + ii;
    float mc = ML[id * 128 + row];
    float lc = ML[id * 128 + 64 + row];
    float s = __expf(mc - M);
    L += lc * s;
    const float* op = Opart + (size_t)id * 8192 + row * 128 + cgp * 16;
    #pragma unroll
    for (int e4 = 0; e4 < 4; ++e4){
      float4 v = *(const float4*)(op + e4 * 4);
      o[e4*4+0] += s * v.x; o[e4*4+1] += s * v.y;
      o[e4*4+2] += s * v.z; o[e4*4+3] += s * v.w;
    }
  }
  float inv = 1.f / L;
  float* dst = out + ((size_t)b * S_LEN + t * 64 + row) * HEAD + cgp * 16;
  #pragma unroll
  for (int e4 = 0; e4 < 4; ++e4){
    float4 w = { o[e4*4]*inv, o[e4*4+1]*inv, o[e4*4+2]*inv, o[e4*4+3]*inv };
    *(float4*)(dst + e4 * 4) = w;
  }
}

// ---------------------------------------------------------------------------
extern "C" void kernel_launch(void* const* d_in, const int* in_sizes, int n_in,
                              void* d_out, int out_size, void* d_ws, size_t ws_size,
                              hipStream_t stream){
  const float* x  = (const float*)d_in[0];
  const float* Wq = (const float*)d_in[1];
  const float* bq = (const float*)d_in[2];
  const float* Wk = (const float*)d_in[3];
  const float* bk = (const float*)d_in[4];
  const float* Wv = (const float*)d_in[5];
  const float* bv = (const float*)d_in[6];
  float* out = (float*)d_out;

  char* ws = (char*)d_ws;
  short* WT    = (short*)(ws);                         // 768 KB
  float* bias  = (float*)(ws + 786432);                // 1.5 KB
  short* Qb    = (short*)(ws + (1u << 20));            // 4 MB
  short* Kb    = (short*)(ws + (1u << 20) + 4194304u); // 4 MB
  short* VTb   = (short*)(ws + (1u << 20) + 8388608u); // 4 MB
  float* Opart = (float*)(ws + 13631488u);             // 640*32KB = 20 MB
  float* ML    = (float*)(ws + 13631488u + 20971520u); // 320 KB

  prep_w<<<1536, 256, 0, stream>>>(Wq, bq, Wk, bk, Wv, bv, WT, bias);
  qkv_proj<<<256, 512, 0, stream>>>(x, WT, bias, Qb, Kb, VTb);
  attn<<<dim3(160, 4), 256, 0, stream>>>(Qb, Kb, VTb, Opart, ML);
  combine<<<dim3(64, 4), 512, 0, stream>>>(Opart, ML, out);
}